// Round 10
// baseline (655.288 us; speedup 1.0000x reference)
//
#include <hip/hip_runtime.h>

#define B_ 2048
#define T_ 200
#define D_ 64

constexpr int TCHUNK = 40;  // t-chunk per block in xpre (5 chunks over T=200)

typedef _Float16 half_t;
typedef __attribute__((ext_vector_type(2))) _Float16 h2;
typedef __attribute__((ext_vector_type(8))) _Float16 h8;

#if defined(__has_builtin)
#if __has_builtin(__builtin_amdgcn_fdot2)
#define HAS_FDOT2 1
#endif
#endif

__device__ __forceinline__ float dot2f(h2 a, h2 b, float c) {
#ifdef HAS_FDOT2
  return __builtin_amdgcn_fdot2(a, b, c, false);
#else
  return fmaf((float)a[0], (float)b[0], fmaf((float)a[1], (float)b[1], c));
#endif
}

__device__ __forceinline__ h2 pick(h8 v, int i) {  // i literal at call sites
  h2 r;
  r[0] = v[2 * i];
  r[1] = v[2 * i + 1];
  return r;
}

__device__ __forceinline__ h8 bc8(uint4 v) { return __builtin_bit_cast(h8, v); }

__device__ __forceinline__ float rcp_(float x) { return __builtin_amdgcn_rcpf(x); }
__device__ __forceinline__ float sigmoidf_(float x) {
  return rcp_(1.0f + __expf(-x));
}
__device__ __forceinline__ float tanhf_(float x) {
  x = fminf(fmaxf(x, -15.0f), 15.0f);
  const float e = __expf(2.0f * x);
  return (e - 1.0f) * rcp_(e + 1.0f);
}

// Packed fp16 weights, one dwordx4 (8 halfs = 8 consecutive k for one output
// column d) per lane per load. i = group*8 + k_octet:
//   groups 0,1,2: h-part r,u,c (k = 64..127)   -> used by rec
//   groups 3,4,5: x-part r,u,c (k = 0..63)     -> used by xpre
__device__ uint4 g_wpk[48 * 64];

__global__ __launch_bounds__(64) void augru_pack(const float* __restrict__ Wg,
                                                 const float* __restrict__ Wc) {
  const int d = threadIdx.x;
  const int i = blockIdx.x;  // 0..47
  const int grp = i >> 3;
  const int io = i & 7;
  const int g = grp % 3;                         // 0=r,1=u,2=c
  const int kbase = (grp >= 3 ? 0 : 64) + io * 8;
  h8 v;
#pragma unroll
  for (int j = 0; j < 8; ++j) {
    const int k = kbase + j;
    float w;
    if (g == 0)      w = Wg[k * 128 + d];
    else if (g == 1) w = Wg[k * 128 + 64 + d];
    else             w = Wc[k * 64 + d];
    v[j] = (half_t)w;
  }
  g_wpk[i * 64 + d] = __builtin_bit_cast(uint4, v);
}

// ---------------- Kernel 1: x-part preactivations ---------------------------
// Writes XP4[t*64+d] = (r_x, u_x) packed halfs, XPC[t*64+d] = c_x half.
__global__ __launch_bounds__(64) void augru_xpre(
    const float* __restrict__ X, const int* __restrict__ SL,
    const float* __restrict__ bg, const float* __restrict__ bc,
    unsigned* __restrict__ XP4, half_t* __restrict__ XPC) {
  __shared__ __align__(16) half_t sX[8][64];

  const int d = threadIdx.x;
  const int chunk = blockIdx.x;
  const int b = blockIdx.y;
  const int L = SL[b];
  const int t0 = chunk * TCHUNK;
  if (t0 >= L) return;
  const int tend = (t0 + TCHUNK < L) ? t0 + TCHUNK : L;

  const float bgr = bg[d];
  const float bgu = bg[64 + d];
  const float bcd = bc[d];

  const float* __restrict__ xrow = X + (size_t)b * (T_ * D_);
  unsigned* __restrict__ o4 = XP4 + (size_t)b * (T_ * 64);
  half_t* __restrict__ oc = XPC + (size_t)b * (T_ * 64);
  const int rr = d >> 3;
  const int c8 = (d & 7) * 8;
  const h8* __restrict__ px = (const h8*)&sX[0][0];

  for (int ts = t0; ts < tend; ts += 8) {
    const float4 fa = *(const float4*)(xrow + (ts + rr) * D_ + c8);
    const float4 fb = *(const float4*)(xrow + (ts + rr) * D_ + c8 + 4);
    h8 hv;
    hv[0] = (half_t)fa.x; hv[1] = (half_t)fa.y;
    hv[2] = (half_t)fa.z; hv[3] = (half_t)fa.w;
    hv[4] = (half_t)fb.x; hv[5] = (half_t)fb.y;
    hv[6] = (half_t)fb.z; hv[7] = (half_t)fb.w;
    *(h8*)(&sX[rr][c8]) = hv;
    asm volatile("" ::: "memory");  // same-wave DS pipe is in-order

#pragma unroll
    for (int r8 = 0; r8 < 8; ++r8) {
      const int t = ts + r8;
      if (t >= tend) break;  // wave-uniform
      // Opaque per-iteration pointer: loads must stream (cheap dwordx4,
      // L1-hot) instead of being hoisted into registers and spilled.
      const uint4* wxp = g_wpk + 24 * 64;
      asm volatile("" : "+s"(wxp));
      float r0 = bgr, r1 = 0.f, u0 = bgu, u1 = 0.f, c0 = bcd, c1 = 0.f;
#define XQ(Q)                                              \
  {                                                        \
    const h8 xb = px[r8 * 8 + (Q)];                        \
    const h8 wr_ = bc8(wxp[(Q)*64 + d]);                   \
    const h8 wu_ = bc8(wxp[(8 + (Q)) * 64 + d]);           \
    const h8 wc_ = bc8(wxp[(16 + (Q)) * 64 + d]);          \
    r0 = dot2f(pick(xb, 0), pick(wr_, 0), r0);             \
    r1 = dot2f(pick(xb, 1), pick(wr_, 1), r1);             \
    r0 = dot2f(pick(xb, 2), pick(wr_, 2), r0);             \
    r1 = dot2f(pick(xb, 3), pick(wr_, 3), r1);             \
    u0 = dot2f(pick(xb, 0), pick(wu_, 0), u0);             \
    u1 = dot2f(pick(xb, 1), pick(wu_, 1), u1);             \
    u0 = dot2f(pick(xb, 2), pick(wu_, 2), u0);             \
    u1 = dot2f(pick(xb, 3), pick(wu_, 3), u1);             \
    c0 = dot2f(pick(xb, 0), pick(wc_, 0), c0);             \
    c1 = dot2f(pick(xb, 1), pick(wc_, 1), c1);             \
    c0 = dot2f(pick(xb, 2), pick(wc_, 2), c0);             \
    c1 = dot2f(pick(xb, 3), pick(wc_, 3), c1);             \
  }
      XQ(0) XQ(1) XQ(2) XQ(3) XQ(4) XQ(5) XQ(6) XQ(7)
#undef XQ
      h2 ru;
      ru[0] = (half_t)(r0 + r1);
      ru[1] = (half_t)(u0 + u1);
      o4[t * 64 + d] = __builtin_bit_cast(unsigned, ru);
      oc[t * 64 + d] = (half_t)(c0 + c1);
    }
    asm volatile("" ::: "memory");
  }
}

// ---------------- Kernel 2: recurrence (h-part, streamed weights) ----------
__global__ __launch_bounds__(64) void augru_rec(
    const unsigned* __restrict__ XP4, const half_t* __restrict__ XPC,
    const int* __restrict__ SL, const float* __restrict__ ATT,
    float* __restrict__ OUT) {
  __shared__ __align__(16) half_t sH[64];
  __shared__ __align__(16) half_t sR[64];

  const int d = threadIdx.x;
  const int b = blockIdx.x;
  const int L = SL[b];  // >= 1

  const unsigned* __restrict__ xp4 = XP4 + (size_t)b * (T_ * 64) + d;
  const half_t* __restrict__ xpc = XPC + (size_t)b * (T_ * 64) + d;
  const float* __restrict__ arow = ATT + (size_t)b * T_;
  float* __restrict__ orow = OUT + (size_t)b * (T_ * D_);
  const h8* __restrict__ ph = (const h8*)sH;
  const h8* __restrict__ pr = (const h8*)sR;

  // h broadcast registers (h0 = 0).
  h8 hb0, hb1, hb2, hb3, hb4, hb5, hb6, hb7;
  {
    h8 z;
#pragma unroll
    for (int i = 0; i < 8; ++i) z[i] = (half_t)0.f;
    hb0 = z; hb1 = z; hb2 = z; hb3 = z; hb4 = z; hb5 = z; hb6 = z; hb7 = z;
  }

  // 2-deep prefetch rotation for Xp (ru dword + c half) and att.
  unsigned ru0 = xp4[0];
  half_t xc0v = xpc[0];
  float a0 = arow[0];
  const int i1 = (1 < L) ? 1 : 0;
  unsigned ru1 = xp4[(size_t)i1 * 64];
  half_t xc1v = xpc[(size_t)i1 * 64];
  float a1 = arow[i1];

  float h = 0.0f;

  for (int t = 0; t < L; ++t) {
    // Opaque per-iteration base: weight loads stream from L1 every step
    // (24 x dwordx4), never hoisted-and-spilled (rounds 2-8 pathology).
    const uint4* whp = g_wpk;
    asm volatile("" : "+s"(whp));

    // Prefetch t+2 (clamped).
    const int t2 = (t + 2 < L) ? t + 2 : (L - 1);
    const unsigned tru = xp4[(size_t)t2 * 64];
    const half_t tc = xpc[(size_t)t2 * 64];
    const float ta = arow[t2];

    const h2 ruh = __builtin_bit_cast(h2, ru0);
    float ar0 = (float)ruh[0], ar1 = 0.f, au0 = (float)ruh[1], au1 = 0.f;
#define GQ(Q)                                              \
  {                                                        \
    const h8 wr_ = bc8(whp[(Q)*64 + d]);                   \
    const h8 wu_ = bc8(whp[(8 + (Q)) * 64 + d]);           \
    ar0 = dot2f(pick(hb##Q, 0), pick(wr_, 0), ar0);        \
    ar1 = dot2f(pick(hb##Q, 1), pick(wr_, 1), ar1);        \
    ar0 = dot2f(pick(hb##Q, 2), pick(wr_, 2), ar0);        \
    ar1 = dot2f(pick(hb##Q, 3), pick(wr_, 3), ar1);        \
    au0 = dot2f(pick(hb##Q, 0), pick(wu_, 0), au0);        \
    au1 = dot2f(pick(hb##Q, 1), pick(wu_, 1), au1);        \
    au0 = dot2f(pick(hb##Q, 2), pick(wu_, 2), au0);        \
    au1 = dot2f(pick(hb##Q, 3), pick(wu_, 3), au1);        \
  }
    GQ(0) GQ(1) GQ(2) GQ(3) GQ(4) GQ(5) GQ(6) GQ(7)
#undef GQ
    const float r = sigmoidf_(ar0 + ar1);
    sR[d] = (half_t)(r * h);
    asm volatile("" ::: "memory");

    const float u = sigmoidf_(au0 + au1);
    const float ua = a0 * u;

    float ac0 = (float)xc0v, ac1 = 0.f;
#define CQ(Q)                                              \
  {                                                        \
    const h8 rb = pr[Q];                                   \
    const h8 wc_ = bc8(whp[(16 + (Q)) * 64 + d]);          \
    ac0 = dot2f(pick(rb, 0), pick(wc_, 0), ac0);           \
    ac1 = dot2f(pick(rb, 1), pick(wc_, 1), ac1);           \
    ac0 = dot2f(pick(rb, 2), pick(wc_, 2), ac0);           \
    ac1 = dot2f(pick(rb, 3), pick(wc_, 3), ac1);           \
  }
    CQ(0) CQ(1) CQ(2) CQ(3) CQ(4) CQ(5) CQ(6) CQ(7)
#undef CQ
    const float c = tanhf_(ac0 + ac1);

    h = fmaf(ua, c - h, h);  // (1-ua)*h + ua*c

    // Stage h for the NEXT step; latency hides under store + rotation.
    sH[d] = (half_t)h;
    asm volatile("" ::: "memory");
    hb0 = ph[0]; hb1 = ph[1]; hb2 = ph[2]; hb3 = ph[3];
    hb4 = ph[4]; hb5 = ph[5]; hb6 = ph[6]; hb7 = ph[7];

    orow[t * D_ + d] = h;

    ru0 = ru1; xc0v = xc1v; a0 = a1;
    ru1 = tru; xc1v = tc; a1 = ta;
  }

  for (int t = L; t < T_; ++t) orow[t * D_ + d] = 0.0f;
}

// ---------------- Fallback (round-2 kernel, used only if ws too small) -----
typedef __attribute__((ext_vector_type(2))) _Float16 h2f;
constexpr int FWAVES = 4;
constexpr int FBLK = FWAVES * 64;
constexpr int FNBLK = B_ / FWAVES;

__device__ __forceinline__ h2 mkh2(float a, float b) {
  h2 r;
  r[0] = (half_t)a;
  r[1] = (half_t)b;
  return r;
}

__global__ __launch_bounds__(FBLK, 2) void augru_dot2(
    const float* __restrict__ X, const int* __restrict__ SL,
    const float* __restrict__ ATT, const float* __restrict__ Wg,
    const float* __restrict__ bg, const float* __restrict__ Wc,
    const float* __restrict__ bc, float* __restrict__ OUT) {
  __shared__ __align__(16) half_t sV[FWAVES][192];

  const int tid = threadIdx.x;
  const int wave = tid >> 6;
  const int d = tid & 63;
  const int b = blockIdx.x * FWAVES + wave;

  h2 wr[64], wu[64], wc[64];
#pragma unroll
  for (int k2 = 0; k2 < 64; ++k2) {
    wr[k2] = mkh2(Wg[(2 * k2) * 128 + d], Wg[(2 * k2 + 1) * 128 + d]);
    wu[k2] = mkh2(Wg[(2 * k2) * 128 + 64 + d], Wg[(2 * k2 + 1) * 128 + 64 + d]);
    wc[k2] = mkh2(Wc[(2 * k2) * 64 + d], Wc[(2 * k2 + 1) * 64 + d]);
  }

  const float bgr = bg[d];
  const float bgu = bg[64 + d];
  const float bcd = bc[d];

  const int L = SL[b];
  const float* __restrict__ xrow = X + (size_t)b * (T_ * D_);
  const float* __restrict__ arow = ATT + (size_t)b * T_;
  float* __restrict__ orow = OUT + (size_t)b * (T_ * D_);

  half_t* __restrict__ vh = &sV[wave][0];
  const uint4* __restrict__ v4p = (const uint4*)vh;

  float h = 0.0f;
  float xn = xrow[d];
  float an = arow[0];

  for (int t = 0; t < L; ++t) {
    const float a_t = an;
    vh[d] = (half_t)xn;
    vh[64 + d] = (half_t)h;
    asm volatile("s_waitcnt lgkmcnt(0)" ::: "memory");

    const int tn = (t + 1 < L) ? t + 1 : t;
    const float xnn = xrow[tn * D_ + d];
    const float ann = arow[tn];

    float ar = bgr, au = bgu, ac = bcd;
#pragma unroll
    for (int q = 0; q < 16; ++q) {
      const uint4 blk = v4p[q];
      const h2 e0 = __builtin_bit_cast(h2, blk.x);
      const h2 e1 = __builtin_bit_cast(h2, blk.y);
      const h2 e2 = __builtin_bit_cast(h2, blk.z);
      const h2 e3 = __builtin_bit_cast(h2, blk.w);
      ar = dot2f(e0, wr[4 * q + 0], ar);
      ar = dot2f(e1, wr[4 * q + 1], ar);
      ar = dot2f(e2, wr[4 * q + 2], ar);
      ar = dot2f(e3, wr[4 * q + 3], ar);
      au = dot2f(e0, wu[4 * q + 0], au);
      au = dot2f(e1, wu[4 * q + 1], au);
      au = dot2f(e2, wu[4 * q + 2], au);
      au = dot2f(e3, wu[4 * q + 3], au);
      if (q < 8) {
        ac = dot2f(e0, wc[4 * q + 0], ac);
        ac = dot2f(e1, wc[4 * q + 1], ac);
        ac = dot2f(e2, wc[4 * q + 2], ac);
        ac = dot2f(e3, wc[4 * q + 3], ac);
      }
    }

    const float r = sigmoidf_(ar);
    const float u = sigmoidf_(au);

    vh[128 + d] = (half_t)(r * h);
    asm volatile("s_waitcnt lgkmcnt(0)" ::: "memory");

#pragma unroll
    for (int q = 0; q < 8; ++q) {
      const uint4 blk = v4p[16 + q];
      const h2 e0 = __builtin_bit_cast(h2, blk.x);
      const h2 e1 = __builtin_bit_cast(h2, blk.y);
      const h2 e2 = __builtin_bit_cast(h2, blk.z);
      const h2 e3 = __builtin_bit_cast(h2, blk.w);
      ac = dot2f(e0, wc[32 + 4 * q + 0], ac);
      ac = dot2f(e1, wc[32 + 4 * q + 1], ac);
      ac = dot2f(e2, wc[32 + 4 * q + 2], ac);
      ac = dot2f(e3, wc[32 + 4 * q + 3], ac);
    }

    const float c = tanhf_(ac);
    const float ua = a_t * u;
    h = fmaf(ua, c - h, h);
    orow[t * D_ + d] = h;

    xn = xnn;
    an = ann;
  }

  for (int t = L; t < T_; ++t) orow[t * D_ + d] = 0.0f;
}

extern "C" void kernel_launch(void* const* d_in, const int* in_sizes, int n_in,
                              void* d_out, int out_size, void* d_ws, size_t ws_size,
                              hipStream_t stream) {
  (void)in_sizes; (void)n_in; (void)out_size;
  const float* X  = (const float*)d_in[0];
  const int*   SL = (const int*)d_in[1];
  const float* A  = (const float*)d_in[2];
  const float* Wg = (const float*)d_in[3];
  const float* bg = (const float*)d_in[4];
  const float* Wc = (const float*)d_in[5];
  const float* bc = (const float*)d_in[6];
  float* O = (float*)d_out;

  const size_t xp4_bytes = (size_t)B_ * T_ * 64 * 4;  // 104.9 MB
  const size_t xpc_bytes = (size_t)B_ * T_ * 64 * 2;  // 52.4 MB
  const size_t need = xp4_bytes + xpc_bytes;          // 157.3 MB (same as r5)

  if (ws_size >= need) {
    unsigned* XP4 = (unsigned*)d_ws;
    half_t* XPC = (half_t*)((char*)d_ws + xp4_bytes);
    augru_pack<<<48, 64, 0, stream>>>(Wg, Wc);
    dim3 grid(T_ / TCHUNK, B_);
    augru_xpre<<<grid, 64, 0, stream>>>(X, SL, bg, bc, XP4, XPC);
    augru_rec<<<B_, 64, 0, stream>>>(XP4, XPC, SL, A, O);
  } else {
    augru_dot2<<<FNBLK, FBLK, 0, stream>>>(X, SL, A, Wg, bg, Wc, bc, O);
  }
}

// Round 11
// 164.091 us; speedup vs baseline: 3.9935x; 3.9935x over previous
//
#include <hip/hip_runtime.h>

#define B_ 2048
#define T_ 200
#define D_ 64

typedef _Float16 half_t;
typedef __attribute__((ext_vector_type(8))) _Float16 h8;
typedef __attribute__((ext_vector_type(4))) float f32x4;

// D = A(16x32) * B(32x16) + C, fp16 in / fp32 acc.  [layouts HW-verified r9]
// A: lane l holds A[row=l&15][k=(l>>4)*8+j]
// B: lane l holds B[k=(l>>4)*8+j][col=l&15]
// C/D: lane l holds D[row=(l>>4)*4+reg][col=l&15]
__device__ __forceinline__ f32x4 MF(h8 a, h8 b, f32x4 c) {
  return __builtin_amdgcn_mfma_f32_16x16x32_f16(a, b, c, 0, 0, 0);
}

__device__ __forceinline__ float rcp_(float x) { return __builtin_amdgcn_rcpf(x); }
__device__ __forceinline__ float sigmoidf_(float x) { return rcp_(1.0f + __expf(-x)); }
__device__ __forceinline__ float tanhf_(float x) {
  x = fminf(fmaxf(x, -15.0f), 15.0f);
  const float e = __expf(2.0f * x);
  return (e - 1.0f) * rcp_(e + 1.0f);
}

__device__ __forceinline__ h8 loadB(const float* __restrict__ W, int stride,
                                    int k0, int col) {
  h8 v;
#pragma unroll
  for (int j = 0; j < 8; ++j) v[j] = (half_t)W[(k0 + j) * stride + col];
  return v;
}

// 16 batch rows per block, 4 waves split the N (output-column) dimension:
// wave w owns cols 16w..16w+15 of {r, u, c, h}. Per-wave weights = 12
// B-fragments = 48 VGPRs (register-resident; the 96-reg ask of rounds 2-8 is
// what the allocator refused). Per step: 12 MFMA, no weight loads, 4KB LDS
// bounce for h/rh layout crossing, 2 barriers (uniform trip count).
__global__ __launch_bounds__(256) __attribute__((amdgpu_waves_per_eu(1)))
void augru_mfma4(const float* __restrict__ X, const int* __restrict__ SL,
                 const float* __restrict__ ATT, const float* __restrict__ Wg,
                 const float* __restrict__ bg, const float* __restrict__ Wc,
                 const float* __restrict__ bc, float* __restrict__ OUT) {
  __shared__ __align__(16) half_t sAh[2][512];  // h in A-layout (k 64..127)
  __shared__ __align__(16) half_t sRh[2][512];  // r*h in A-layout

  const int tid = threadIdx.x;
  const int w = tid >> 6;    // wave 0..3
  const int l = tid & 63;
  const int b0 = blockIdx.x * 16;
  const int rA = l & 15;     // A row / D col-within-tile
  const int kq = l >> 4;     // k-octet group / D row-quarter
  const int rowD = kq * 4;   // D rows rowD..rowD+3
  const int colW = 16 * w + rA;  // this wave's global output column (0..63)
  // A-layout address for element (row=rowD+reg, col=colW):
  const int ksl = colW >> 5;
  const int c32 = colW & 31;
  const int baseA = (rowD + 16 * (c32 >> 3)) * 8 + (c32 & 7);

  // ---- B-fragments in registers (12 x h8 = 48 VGPRs) ----
  const h8 bgr0 = loadB(Wg, 128, 0 + kq * 8, colW);
  const h8 bgr1 = loadB(Wg, 128, 32 + kq * 8, colW);
  const h8 bgr2 = loadB(Wg, 128, 64 + kq * 8, colW);
  const h8 bgr3 = loadB(Wg, 128, 96 + kq * 8, colW);
  const h8 bgu0 = loadB(Wg, 128, 0 + kq * 8, 64 + colW);
  const h8 bgu1 = loadB(Wg, 128, 32 + kq * 8, 64 + colW);
  const h8 bgu2 = loadB(Wg, 128, 64 + kq * 8, 64 + colW);
  const h8 bgu3 = loadB(Wg, 128, 96 + kq * 8, 64 + colW);
  const h8 bcc0 = loadB(Wc, 64, 0 + kq * 8, colW);
  const h8 bcc1 = loadB(Wc, 64, 32 + kq * 8, colW);
  const h8 bcc2 = loadB(Wc, 64, 64 + kq * 8, colW);
  const h8 bcc3 = loadB(Wc, 64, 96 + kq * 8, colW);

  // Zero h state (h0 = 0): sAh is 1024 halfs = 128 h8.
  if (tid < 128) {
    h8 z;
#pragma unroll
    for (int j = 0; j < 8; ++j) z[j] = (half_t)0.f;
    ((h8*)&sAh[0][0])[tid] = z;
  }

  const float br = bg[colW];
  const float bu = bg[64 + colW];
  const float bcv = bc[colW];

  const int L0 = SL[b0 + rowD + 0];
  const int L1 = SL[b0 + rowD + 1];
  const int L2 = SL[b0 + rowD + 2];
  const int L3 = SL[b0 + rowD + 3];
  int Lm = 1;
  for (int r = 0; r < 16; ++r) {
    const int v = SL[b0 + r];
    Lm = v > Lm ? v : Lm;
  }

  const float* __restrict__ xbase = X + (size_t)(b0 + rA) * (T_ * D_) + kq * 8;
  const float* __restrict__ ap = ATT + (size_t)(b0 + rowD) * T_;
  float* __restrict__ obase = OUT + (size_t)b0 * (T_ * D_);

  // x/att prefetch for t=0
  f32x4 xA0 = *(const f32x4*)(xbase);
  f32x4 xA1 = *(const f32x4*)(xbase + 4);
  f32x4 xB0 = *(const f32x4*)(xbase + 32);
  f32x4 xB1 = *(const f32x4*)(xbase + 36);
  float at0 = ap[0], at1 = ap[T_], at2 = ap[2 * T_], at3 = ap[3 * T_];

  float hd0 = 0.f, hd1 = 0.f, hd2 = 0.f, hd3 = 0.f;

  __syncthreads();  // sAh zero visible

  for (int t = 0; t < Lm; ++t) {
    // h A-fragments (all waves read the full 16x64 h tile)
    const h8 ah0 = ((const h8*)&sAh[0][0])[l];
    const h8 ah1 = ((const h8*)&sAh[1][0])[l];

    // x -> fp16 A-fragments
    h8 ax0, ax1;
#pragma unroll
    for (int j = 0; j < 4; ++j) {
      ax0[j] = (half_t)xA0[j];
      ax0[4 + j] = (half_t)xA1[j];
      ax1[j] = (half_t)xB0[j];
      ax1[4 + j] = (half_t)xB1[j];
    }

    // prefetch t+1 (clamped) — hidden under MFMA chains
    const int tn = (t + 1 < Lm) ? t + 1 : t;
    const f32x4 nA0 = *(const f32x4*)(xbase + tn * 64);
    const f32x4 nA1 = *(const f32x4*)(xbase + tn * 64 + 4);
    const f32x4 nB0 = *(const f32x4*)(xbase + tn * 64 + 32);
    const f32x4 nB1 = *(const f32x4*)(xbase + tn * 64 + 36);
    const float na0 = ap[tn], na1 = ap[T_ + tn], na2 = ap[2 * T_ + tn],
                na3 = ap[3 * T_ + tn];

    // ---- r gate (critical path) ----
    f32x4 gr = {br, br, br, br};
    gr = MF(ax0, bgr0, gr);
    gr = MF(ax1, bgr1, gr);
    gr = MF(ah0, bgr2, gr);
    gr = MF(ah1, bgr3, gr);

    // stage rh = sigmoid(gr) * h_old into A-layout
    sRh[ksl][baseA + 0 * 8] = (half_t)(sigmoidf_(gr[0]) * hd0);
    sRh[ksl][baseA + 1 * 8] = (half_t)(sigmoidf_(gr[1]) * hd1);
    sRh[ksl][baseA + 2 * 8] = (half_t)(sigmoidf_(gr[2]) * hd2);
    sRh[ksl][baseA + 3 * 8] = (half_t)(sigmoidf_(gr[3]) * hd3);

    // ---- u gate (independent; fills time before the barrier) ----
    f32x4 gu = {bu, bu, bu, bu};
    gu = MF(ax0, bgu0, gu);
    gu = MF(ax1, bgu1, gu);
    gu = MF(ah0, bgu2, gu);
    gu = MF(ah1, bgu3, gu);

    __syncthreads();  // B1: all rh written

    const h8 arh0 = ((const h8*)&sRh[0][0])[l];
    const h8 arh1 = ((const h8*)&sRh[1][0])[l];

    // ---- candidate ----
    f32x4 cc = {bcv, bcv, bcv, bcv};
    cc = MF(ax0, bcc0, cc);
    cc = MF(ax1, bcc1, cc);
    cc = MF(arh0, bcc2, cc);
    cc = MF(arh1, bcc3, cc);

    // ---- blend, mask, store, stage h ----
#define FIN(i, HD, AT, LI)                                                  \
  {                                                                         \
    const float uv = sigmoidf_(gu[i]);                                      \
    const float cv = tanhf_(cc[i]);                                         \
    const float hn0 = fmaf(AT * uv, cv - HD, HD);                           \
    const bool ok = t < LI;                                                 \
    const float hn = ok ? hn0 : HD;                                         \
    HD = hn;                                                                \
    obase[(size_t)(rowD + i) * (T_ * D_) + t * 64 + colW] = ok ? hn : 0.0f; \
    sAh[ksl][baseA + i * 8] = (half_t)hn;                                   \
  }
    FIN(0, hd0, at0, L0)
    FIN(1, hd1, at1, L1)
    FIN(2, hd2, at2, L2)
    FIN(3, hd3, at3, L3)
#undef FIN

    __syncthreads();  // B2: all h written before next step's reads

    xA0 = nA0; xA1 = nA1; xB0 = nB0; xB1 = nB1;
    at0 = na0; at1 = na1; at2 = na2; at3 = na3;
  }

  // zero-fill past the block's max length (each wave covers its 16 cols)
  for (int t = Lm; t < T_; ++t) {
    obase[(size_t)(rowD + 0) * (T_ * D_) + t * 64 + colW] = 0.0f;
    obase[(size_t)(rowD + 1) * (T_ * D_) + t * 64 + colW] = 0.0f;
    obase[(size_t)(rowD + 2) * (T_ * D_) + t * 64 + colW] = 0.0f;
    obase[(size_t)(rowD + 3) * (T_ * D_) + t * 64 + colW] = 0.0f;
  }
}

extern "C" void kernel_launch(void* const* d_in, const int* in_sizes, int n_in,
                              void* d_out, int out_size, void* d_ws, size_t ws_size,
                              hipStream_t stream) {
  (void)in_sizes; (void)n_in; (void)d_ws; (void)ws_size; (void)out_size;
  const float* X  = (const float*)d_in[0];
  const int*   SL = (const int*)d_in[1];
  const float* A  = (const float*)d_in[2];
  const float* Wg = (const float*)d_in[3];
  const float* bg = (const float*)d_in[4];
  const float* Wc = (const float*)d_in[5];
  const float* bc = (const float*)d_in[6];
  float* O = (float*)d_out;

  augru_mfma4<<<B_ / 16, 256, 0, stream>>>(X, SL, A, Wg, bg, Wc, bc, O);
}